// Round 1
// baseline (378.287 us; speedup 1.0000x reference)
//
#include <hip/hip_runtime.h>

#define NN 100000
#define NE 1600000
#define F_IN 128
#define DIM 64
#define NC 40
#define MAXDEG 64

// ---------- adjacency build: padded slots, 64 per node ----------
__global__ __launch_bounds__(256) void k_build(const int* __restrict__ src,
                                               const int* __restrict__ dst,
                                               int* __restrict__ cnt,
                                               int* __restrict__ slots) {
  int e = blockIdx.x * 256 + threadIdx.x;
  if (e >= NE) return;
  int d = dst[e];
  int pos = atomicAdd(&cnt[d], 1);
  if (pos < MAXDEG) slots[(size_t)d * MAXDEG + pos] = src[e];
}

// ---------- y = x @ W1 (no bias), 16 nodes/block, lane = out column ----------
__global__ __launch_bounds__(256) void k_gemm1(const float* __restrict__ x,
                                               const float* __restrict__ W1,
                                               float* __restrict__ y) {
  __shared__ float xs[16][F_IN];
  int tid = threadIdx.x;
  int wv = tid >> 6, c = tid & 63;
  float w[F_IN];
#pragma unroll
  for (int k = 0; k < F_IN; ++k) w[k] = W1[k * DIM + c];
  int node0 = blockIdx.x * 16;
  const float4* xsrc = (const float4*)(x + (size_t)node0 * F_IN);
  float4* xdst = (float4*)&xs[0][0];
  for (int i = tid; i < 16 * F_IN / 4; i += 256) xdst[i] = xsrc[i];
  __syncthreads();
#pragma unroll
  for (int i = 0; i < 4; ++i) {
    int r = wv * 4 + i;
    float acc = 0.f;
#pragma unroll
    for (int k = 0; k < F_IN; k += 4) {
      float4 xv = *(const float4*)&xs[r][k];
      acc += xv.x * w[k] + xv.y * w[k + 1] + xv.z * w[k + 2] + xv.w * w[k + 3];
    }
    y[(size_t)(node0 + r) * DIM + c] = acc;
  }
}

// ---------- a[n] = sum_{e: dst=n} y[src_e], one wave per node ----------
__global__ __launch_bounds__(256) void k_agg(const float* __restrict__ y,
                                             const int* __restrict__ cnt,
                                             const int* __restrict__ slots,
                                             float* __restrict__ a) {
  int wv = threadIdx.x >> 6, lane = threadIdx.x & 63;
  int n = blockIdx.x * 4 + wv;
  int c = cnt[n];
  c = c > MAXDEG ? MAXDEG : c;
  const int* sl = slots + (size_t)n * MAXDEG;
  int sv = sl[lane];  // coalesced read of this node's slot list
  float acc = 0.f;
  int j = 0;
  for (; j + 4 <= c; j += 4) {
    int s0 = __shfl(sv, j), s1 = __shfl(sv, j + 1);
    int s2 = __shfl(sv, j + 2), s3 = __shfl(sv, j + 3);
    float v0 = y[(size_t)s0 * DIM + lane];
    float v1 = y[(size_t)s1 * DIM + lane];
    float v2 = y[(size_t)s2 * DIM + lane];
    float v3 = y[(size_t)s3 * DIM + lane];
    acc += v0; acc += v1; acc += v2; acc += v3;
  }
  for (; j < c; ++j) {
    int s = __shfl(sv, j);
    acc += y[(size_t)s * DIM + lane];
  }
  a[(size_t)n * DIM + lane] = acc;
}

// ---------- h1 = relu(y + a + b1); y <- h1 @ W2 (in-place) ----------
__global__ __launch_bounds__(256) void k_mid(float* __restrict__ y,
                                             const float* __restrict__ a,
                                             const float* __restrict__ W2,
                                             const float* __restrict__ b1) {
  __shared__ float hs[16][DIM];
  int tid = threadIdx.x, wv = tid >> 6, c = tid & 63;
  float w[DIM];
#pragma unroll
  for (int k = 0; k < DIM; ++k) w[k] = W2[k * DIM + c];
  float b1c = b1[c];
  int node0 = blockIdx.x * 16;
#pragma unroll
  for (int i = 0; i < 4; ++i) {
    int r = wv * 4 + i;
    size_t idx = (size_t)(node0 + r) * DIM + c;
    hs[r][c] = fmaxf(y[idx] + a[idx] + b1c, 0.f);
  }
  __syncthreads();
#pragma unroll
  for (int i = 0; i < 4; ++i) {
    int r = wv * 4 + i;
    float acc = 0.f;
#pragma unroll
    for (int k = 0; k < DIM; k += 4) {
      float4 hv = *(const float4*)&hs[r][k];
      acc += hv.x * w[k] + hv.y * w[k + 1] + hv.z * w[k + 2] + hv.w * w[k + 3];
    }
    y[(size_t)(node0 + r) * DIM + c] = acc;
  }
}

// ---------- h2=relu(y+a+b2); h3=relu(h2@Wf1+bf1); out=log_softmax(h3@Wf2+bf2) ----------
__global__ __launch_bounds__(256) void k_final(const float* __restrict__ y,
                                               const float* __restrict__ a,
                                               const float* __restrict__ b2,
                                               const float* __restrict__ Wf1,
                                               const float* __restrict__ bf1,
                                               const float* __restrict__ Wf2,
                                               const float* __restrict__ bf2,
                                               float* __restrict__ out) {
  __shared__ float hs[16][DIM];
  __shared__ float hs2[16][DIM];
  int tid = threadIdx.x, wv = tid >> 6, c = tid & 63;
  float w1r[DIM];
#pragma unroll
  for (int k = 0; k < DIM; ++k) w1r[k] = Wf1[k * DIM + c];
  float w2r[DIM];
  if (c < NC) {
#pragma unroll
    for (int k = 0; k < DIM; ++k) w2r[k] = Wf2[k * NC + c];
  } else {
#pragma unroll
    for (int k = 0; k < DIM; ++k) w2r[k] = 0.f;
  }
  float b2c = b2[c], bf1c = bf1[c];
  float bf2c = (c < NC) ? bf2[c] : 0.f;
  int node0 = blockIdx.x * 16;
#pragma unroll
  for (int i = 0; i < 4; ++i) {
    int r = wv * 4 + i;
    size_t idx = (size_t)(node0 + r) * DIM + c;
    hs[r][c] = fmaxf(y[idx] + a[idx] + b2c, 0.f);
  }
  __syncthreads();
#pragma unroll
  for (int i = 0; i < 4; ++i) {
    int r = wv * 4 + i;
    float acc = bf1c;
#pragma unroll
    for (int k = 0; k < DIM; k += 4) {
      float4 hv = *(const float4*)&hs[r][k];
      acc += hv.x * w1r[k] + hv.y * w1r[k + 1] + hv.z * w1r[k + 2] + hv.w * w1r[k + 3];
    }
    hs2[r][c] = fmaxf(acc, 0.f);
  }
  __syncthreads();
#pragma unroll
  for (int i = 0; i < 4; ++i) {
    int r = wv * 4 + i;
    float l = bf2c;
#pragma unroll
    for (int k = 0; k < DIM; k += 4) {
      float4 hv = *(const float4*)&hs2[r][k];
      l += hv.x * w2r[k] + hv.y * w2r[k + 1] + hv.z * w2r[k + 2] + hv.w * w2r[k + 3];
    }
    float m = (c < NC) ? l : -1e30f;
#pragma unroll
    for (int off = 32; off >= 1; off >>= 1) m = fmaxf(m, __shfl_xor(m, off));
    float ex = (c < NC) ? __expf(l - m) : 0.f;
    float s = ex;
#pragma unroll
    for (int off = 32; off >= 1; off >>= 1) s += __shfl_xor(s, off);
    if (c < NC) out[(size_t)(node0 + r) * NC + c] = l - m - __logf(s);
  }
}

extern "C" void kernel_launch(void* const* d_in, const int* in_sizes, int n_in,
                              void* d_out, int out_size, void* d_ws, size_t ws_size,
                              hipStream_t stream) {
  const float* x   = (const float*)d_in[0];
  const int*   ei  = (const int*)d_in[1];
  const float* W1  = (const float*)d_in[2];
  const float* b1  = (const float*)d_in[3];
  const float* W2  = (const float*)d_in[4];
  const float* b2  = (const float*)d_in[5];
  const float* Wf1 = (const float*)d_in[6];
  const float* bf1 = (const float*)d_in[7];
  const float* Wf2 = (const float*)d_in[8];
  const float* bf2 = (const float*)d_in[9];
  float* out = (float*)d_out;

  char* ws = (char*)d_ws;
  int*   cnt   = (int*)ws;                                  // 0.4 MB
  int*   slots = (int*)(ws + (1u << 20));                   // 25.6 MB
  float* y     = (float*)(ws + (1u << 20) + 25600000u);     // 25.6 MB
  float* a     = (float*)(ws + (1u << 20) + 51200000u);     // 25.6 MB

  const int* src = ei;
  const int* dst = ei + NE;

  hipMemsetAsync(cnt, 0, NN * sizeof(int), stream);
  k_build<<<(NE + 255) / 256, 256, 0, stream>>>(src, dst, cnt, slots);
  k_gemm1<<<NN / 16, 256, 0, stream>>>(x, W1, y);
  k_agg<<<NN / 4, 256, 0, stream>>>(y, cnt, slots, a);
  k_mid<<<NN / 16, 256, 0, stream>>>(y, a, W2, b1);
  k_agg<<<NN / 4, 256, 0, stream>>>(y, cnt, slots, a);
  k_final<<<NN / 16, 256, 0, stream>>>(y, a, b2, Wf1, bf1, Wf2, bf2, out);
}